// Round 13
// baseline (323.078 us; speedup 1.0000x reference)
//
#include <hip/hip_runtime.h>
#include <hip/hip_cooperative_groups.h>

namespace cg = cooperative_groups;

#define NPTS 8192
#define KNN 8
// phase A (subset) geometry
#define NSUB 4096
#define ASLICE 256
#define NSLICE_A (NSUB / ASLICE)  // 16
// phase C (full gated scan) geometry
#define CSLICE 512
#define NSLICE_C (NPTS / CSLICE)  // 16

typedef short bf16x8 __attribute__((ext_vector_type(8)));
typedef float f32x4 __attribute__((ext_vector_type(4)));

// bf16 round-to-nearest-even split helpers.
__device__ __forceinline__ unsigned short f2bf(float x) {
  unsigned int u = __float_as_uint(x);
  return (unsigned short)((u + 0x7FFF + ((u >> 16) & 1)) >> 16);
}
__device__ __forceinline__ float bf2f(unsigned short s) {
  return __uint_as_float(((unsigned int)s) << 16);
}

// Exact distance, replicating numpy rounding. Same bits every use.
__device__ __forceinline__ float dist_exact(float qx, float qy, float qz,
                                            float q2, float px, float py,
                                            float pz, float p2) {
  float dot = __fmaf_rn(qz, pz, __fmaf_rn(qy, py, __fmul_rn(qx, px)));
  float t1 = __fadd_rn(q2, p2);
  return __fadd_rn(t1, __fmul_rn(-2.0f, dot));
}

__device__ __forceinline__ float norm2_exact(float x, float y, float z) {
  return __fadd_rn(__fadd_rn(__fmul_rn(x, x), __fmul_rn(y, y)),
                   __fmul_rn(z, z));
}

// Monotone (d, idx) -> f64 key (verified R8): lex (d_bits, idx) order ==
// IEEE f64 order; ascending keys == jax.lax.top_k order (stable ties).
__device__ __forceinline__ double pack_key(float d, int idx) {
  unsigned int ub = __float_as_uint(d);
  ub ^= (((unsigned int)((int)ub >> 31)) | 0x80000000u);
  unsigned int lo = (ub << 13) | (unsigned int)idx;
  unsigned int hi = 0x3ff00000u | (ub >> 19);
  return __hiloint2double((int)hi, (int)lo);
}

#define KEY_DECL                                                            \
  const double KINF = __longlong_as_double(0x7ff0000000000000LL);           \
  double k0 = KINF, k1 = KINF, k2 = KINF, k3 = KINF, k4 = KINF, k5 = KINF,  \
         k6 = KINF, k7 = KINF;

// Parallel sorted-insert (med3 identity, verified R9/R12): depth 2, 15 ops.
// Inserting +inf is the identity. Macro temporaries underscore-prefixed
// (R11 failure: caller temp captured by macro-internal name).
#define KEY_INSERT(key)                                                     \
  {                                                                         \
    const double _x = (key);                                                \
    const double _m0 = fmax(_x, k0), _m1 = fmax(_x, k1);                    \
    const double _m2 = fmax(_x, k2), _m3 = fmax(_x, k3);                    \
    const double _m4 = fmax(_x, k4), _m5 = fmax(_x, k5);                    \
    const double _m6 = fmax(_x, k6);                                        \
    k7 = fmin(_m6, k7);                                                     \
    k6 = fmin(_m5, k6);                                                     \
    k5 = fmin(_m4, k5);                                                     \
    k4 = fmin(_m3, k4);                                                     \
    k3 = fmin(_m2, k3);                                                     \
    k2 = fmin(_m1, k2);                                                     \
    k1 = fmin(_m0, k1);                                                     \
    k0 = fmin(_x, k0);                                                      \
  }

// f32 value-only parallel sorted-insert (same med3 identity), 15 f32 ops.
#define VAL_DECL                                                            \
  float v0 = 3.4e38f, v1 = 3.4e38f, v2 = 3.4e38f, v3 = 3.4e38f,            \
        v4 = 3.4e38f, v5 = 3.4e38f, v6 = 3.4e38f, v7 = 3.4e38f;
#define VAL_INSERT(val)                                                     \
  {                                                                         \
    const float _x = (val);                                                 \
    const float _m0 = fmaxf(_x, v0), _m1 = fmaxf(_x, v1);                   \
    const float _m2 = fmaxf(_x, v2), _m3 = fmaxf(_x, v3);                   \
    const float _m4 = fmaxf(_x, v4), _m5 = fmaxf(_x, v5);                   \
    const float _m6 = fmaxf(_x, v6);                                        \
    v7 = fminf(_m6, v7);                                                    \
    v6 = fminf(_m5, v6);                                                    \
    v5 = fminf(_m4, v5);                                                    \
    v4 = fminf(_m3, v4);                                                    \
    v3 = fminf(_m2, v3);                                                    \
    v2 = fminf(_m1, v2);                                                    \
    v1 = fminf(_m0, v1);                                                    \
    v0 = fminf(_x, v0);                                                     \
  }

// ---------------------------------------------------------------------------
// Cooperative KNN mega-kernel: 512 blocks x 256 threads (2 blocks/CU).
//  Phase A: subset scan -> part_v (top-8 f32 values per (q, 256-slice)).
//  grid.sync()
//  Phase C: tau computed inline from part_v (cheap, redundant per block),
//           then ballot-gated full scan -> part_k (f64 keys).
//  grid.sync()
//  Phase D: blocks 0..31 merge 128 keys/query -> nbr.
// ---------------------------------------------------------------------------
__global__ __launch_bounds__(256) void knn_mega_kernel(
    const float* __restrict__ pts, float* __restrict__ part_v,
    double* __restrict__ part_k, int* __restrict__ nbr) {
  __shared__ float4 sp[CSLICE];  // 8 KB, reused by phases A (256) and C (512)
  const int t = threadIdx.x;
  const int bid = blockIdx.x;
  const int qblk = bid & 31;
  const int slice = bid >> 5;  // 0..15
  const int q = qblk * 256 + t;
  cg::grid_group grid = cg::this_grid();

  // ---------------- Phase A: subset values ----------------
  {
    const int jbase = slice * ASLICE;
    float x = pts[(jbase + t) * 3 + 0];
    float y = pts[(jbase + t) * 3 + 1];
    float z = pts[(jbase + t) * 3 + 2];
    sp[t] = make_float4(x, y, z, norm2_exact(x, y, z));
    __syncthreads();
    const float qx = pts[q * 3 + 0], qy = pts[q * 3 + 1],
                qz = pts[q * 3 + 2];
    const float q2 = norm2_exact(qx, qy, qz);
    VAL_DECL;
    for (int p = 0; p < ASLICE; p += 4) {
      float4 c0 = sp[p + 0];
      float4 c1 = sp[p + 1];
      float4 c2 = sp[p + 2];
      float4 c3 = sp[p + 3];
      VAL_INSERT(dist_exact(qx, qy, qz, q2, c0.x, c0.y, c0.z, c0.w));
      VAL_INSERT(dist_exact(qx, qy, qz, q2, c1.x, c1.y, c1.z, c1.w));
      VAL_INSERT(dist_exact(qx, qy, qz, q2, c2.x, c2.y, c2.z, c2.w));
      VAL_INSERT(dist_exact(qx, qy, qz, q2, c3.x, c3.y, c3.z, c3.w));
    }
    float* o = &part_v[(size_t)q * 128 + slice * 8];
    o[0] = v0; o[1] = v1; o[2] = v2; o[3] = v3;
    o[4] = v4; o[5] = v5; o[6] = v6; o[7] = v7;
  }
  grid.sync();

  // ---------------- Phase C: tau (inline) + ballot-gated scan ----------------
  {
    const int jbase = slice * CSLICE;
    for (int p = t; p < CSLICE; p += 256) {
      float x = pts[(jbase + p) * 3 + 0];
      float y = pts[(jbase + p) * 3 + 1];
      float z = pts[(jbase + p) * 3 + 2];
      sp[p] = make_float4(x, y, z, norm2_exact(x, y, z));
    }
    __syncthreads();
    // tau = 8th-smallest over this query's 128 subset values
    float tq;
    {
      const float4* v4p = (const float4*)&part_v[(size_t)q * 128];
      VAL_DECL;
#pragma unroll 8
      for (int u = 0; u < 32; ++u) {
        float4 v = v4p[u];
        VAL_INSERT(v.x);
        VAL_INSERT(v.y);
        VAL_INSERT(v.z);
        VAL_INSERT(v.w);
      }
      tq = v7;
    }
    const float qx = pts[q * 3 + 0], qy = pts[q * 3 + 1],
                qz = pts[q * 3 + 2];
    const float q2 = norm2_exact(qx, qy, qz);
    KEY_DECL;
    for (int p = 0; p < CSLICE; p += 4) {
      float4 c0 = sp[p + 0];
      float4 c1 = sp[p + 1];
      float4 c2 = sp[p + 2];
      float4 c3 = sp[p + 3];
      float e0 = dist_exact(qx, qy, qz, q2, c0.x, c0.y, c0.z, c0.w);
      float e1 = dist_exact(qx, qy, qz, q2, c1.x, c1.y, c1.z, c1.w);
      float e2 = dist_exact(qx, qy, qz, q2, c2.x, c2.y, c2.z, c2.w);
      float e3 = dist_exact(qx, qy, qz, q2, c3.x, c3.y, c3.z, c3.w);
      unsigned long long g0 = __ballot(e0 <= tq);
      unsigned long long g1 = __ballot(e1 <= tq);
      unsigned long long g2 = __ballot(e2 <= tq);
      unsigned long long g3 = __ballot(e3 <= tq);
      if (g0) {
        double key0 = (e0 <= tq) ? pack_key(e0, jbase + p + 0) : KINF;
        KEY_INSERT(key0);
      }
      if (g1) {
        double key1 = (e1 <= tq) ? pack_key(e1, jbase + p + 1) : KINF;
        KEY_INSERT(key1);
      }
      if (g2) {
        double key2 = (e2 <= tq) ? pack_key(e2, jbase + p + 2) : KINF;
        KEY_INSERT(key2);
      }
      if (g3) {
        double key3 = (e3 <= tq) ? pack_key(e3, jbase + p + 3) : KINF;
        KEY_INSERT(key3);
      }
    }
    double* o = &part_k[(size_t)q * 128 + slice * 8];
    o[0] = k0; o[1] = k1; o[2] = k2; o[3] = k3;
    o[4] = k4; o[5] = k5; o[6] = k6; o[7] = k7;
  }
  grid.sync();

  // ---------------- Phase D: merge (blocks 0..31) ----------------
  if (bid < 32) {
    const int qm = bid * 256 + t;
    const double* kv = &part_k[(size_t)qm * 128];
    KEY_DECL;
#pragma unroll 8
    for (int u = 0; u < 128; u += 4) {
      double a = kv[u + 0];
      double b = kv[u + 1];
      double c = kv[u + 2];
      double d = kv[u + 3];
      KEY_INSERT(a);
      KEY_INSERT(b);
      KEY_INSERT(c);
      KEY_INSERT(d);
    }
    nbr[qm * KNN + 0] = __double2loint(k0) & 0x1fff;
    nbr[qm * KNN + 1] = __double2loint(k1) & 0x1fff;
    nbr[qm * KNN + 2] = __double2loint(k2) & 0x1fff;
    nbr[qm * KNN + 3] = __double2loint(k3) & 0x1fff;
    nbr[qm * KNN + 4] = __double2loint(k4) & 0x1fff;
    nbr[qm * KNN + 5] = __double2loint(k5) & 0x1fff;
    nbr[qm * KNN + 6] = __double2loint(k6) & 0x1fff;
    nbr[qm * KNN + 7] = __double2loint(k7) & 0x1fff;
  }
}

// ---------------------------------------------------------------------------
// Prep: split/transpose all weights to bf16 hi/lo.
//  Wcat (from W3, fused):    Wcath/Wcatl[c*128+k], c<256, k<128
//  W4 (128x256):             W4ht/W4lt[c*128+k]
//  W2 (64x128):              W2ht/W2lt[c*64+k]
// ---------------------------------------------------------------------------
__global__ __launch_bounds__(256) void prep_kernel(
    const float* __restrict__ W3, const float* __restrict__ W4,
    const float* __restrict__ W2, unsigned short* __restrict__ Wcath,
    unsigned short* __restrict__ Wcatl, unsigned short* __restrict__ W4ht,
    unsigned short* __restrict__ W4lt, unsigned short* __restrict__ W2ht,
    unsigned short* __restrict__ W2lt) {
  const int id = blockIdx.x * 256 + threadIdx.x;
  if (id < 32768) {
    int k = id >> 8, c = id & 255;
    float v = (c < 128) ? W3[k * 128 + c] : W3[(128 + k) * 128 + (c - 128)];
    unsigned short hi = f2bf(v);
    Wcath[c * 128 + k] = hi;
    Wcatl[c * 128 + k] = f2bf(v - bf2f(hi));
  } else if (id < 65536) {
    int i2 = id - 32768;
    int k = i2 >> 8, c = i2 & 255;
    float v = W4[k * 256 + c];
    unsigned short hi = f2bf(v);
    W4ht[c * 128 + k] = hi;
    W4lt[c * 128 + k] = f2bf(v - bf2f(hi));
  } else if (id < 73728) {
    int i2 = id - 65536;
    int k = i2 >> 7, c = i2 & 127;
    float v = W2[k * 128 + c];
    unsigned short hi = f2bf(v);
    W2ht[c * 64 + k] = hi;
    W2lt[c * 64 + k] = f2bf(v - bf2f(hi));
  }
}

// ---------------------------------------------------------------------------
// MFMA EdgeConv1 (split-bf16): H1 = relu(e@W1+b1) fp32 in-kernel, split;
// W2 pre-split. Epilogue: segmax + b2 + relu -> y stored as SPLIT bf16
// (yh/yl, 8192x128) for the downstream MFMA gemm_ac. grid 512.
// ---------------------------------------------------------------------------
__global__ __launch_bounds__(256) void gemm1_mfma_kernel(
    const float* __restrict__ pts, const int* __restrict__ nbr,
    const float* __restrict__ W1, const float* __restrict__ b1,
    const unsigned short* __restrict__ W2ht,
    const unsigned short* __restrict__ W2lt, const float* __restrict__ b2,
    unsigned short* __restrict__ yh, unsigned short* __restrict__ yl) {
  __shared__ float es[128][6];
  __shared__ float W1s[6][64];
  __shared__ float b1s[64];
  __shared__ unsigned short Ah[128 * 40];
  __shared__ unsigned short Al[128 * 40];
  __shared__ unsigned short Bh[128 * 40];
  __shared__ unsigned short Bl[128 * 40];
  const int t = threadIdx.x;
  const int rowBase = blockIdx.x * 128;
  for (int idx = t; idx < 384; idx += 256) W1s[idx >> 6][idx & 63] = W1[idx];
  if (t < 64) b1s[t] = b1[t];
  if (t < 128) {
    int e = rowBase + t;
    int i = e >> 3;
    int j = nbr[e];
    float xi0 = pts[i * 3], xi1 = pts[i * 3 + 1], xi2 = pts[i * 3 + 2];
    es[t][0] = xi0;
    es[t][1] = xi1;
    es[t][2] = xi2;
    es[t][3] = pts[j * 3] - xi0;
    es[t][4] = pts[j * 3 + 1] - xi1;
    es[t][5] = pts[j * 3 + 2] - xi2;
  }
  __syncthreads();
  const int eloc = t >> 1, hh = t & 1;
  const int kb = hh * 16;
  const float f0 = es[eloc][0], f1 = es[eloc][1], f2 = es[eloc][2];
  const float f3 = es[eloc][3], f4 = es[eloc][4], f5 = es[eloc][5];
  const int lane = t & 63;
  const int w = t >> 6;
  const int q = lane >> 4;
  const int nidx = lane & 15;

  f32x4 acc[2][8];
#pragma unroll
  for (int mt = 0; mt < 2; ++mt)
#pragma unroll
    for (int nt = 0; nt < 8; ++nt) acc[mt][nt] = (f32x4){0.f, 0.f, 0.f, 0.f};

  for (int p = 0; p < 2; ++p) {
    const int k0 = p * 32;
    {
      float h[16];
#pragma unroll
      for (int u4 = 0; u4 < 4; ++u4) {
        int cb = k0 + kb + u4 * 4;
        float4 w0 = *(const float4*)&W1s[0][cb];
        float4 w1 = *(const float4*)&W1s[1][cb];
        float4 w2v = *(const float4*)&W1s[2][cb];
        float4 w3 = *(const float4*)&W1s[3][cb];
        float4 w4v = *(const float4*)&W1s[4][cb];
        float4 w5 = *(const float4*)&W1s[5][cb];
        float4 bb = *(const float4*)&b1s[cb];
        const float* wp[6] = {(float*)&w0, (float*)&w1, (float*)&w2v,
                              (float*)&w3, (float*)&w4v, (float*)&w5};
        const float* bp = (const float*)&bb;
#pragma unroll
        for (int d = 0; d < 4; ++d) {
          float v = bp[d];
          v = fmaf(f0, wp[0][d], v);
          v = fmaf(f1, wp[1][d], v);
          v = fmaf(f2, wp[2][d], v);
          v = fmaf(f3, wp[3][d], v);
          v = fmaf(f4, wp[4][d], v);
          v = fmaf(f5, wp[5][d], v);
          h[u4 * 4 + d] = fmaxf(v, 0.0f);
        }
      }
      unsigned int hp[8], lp[8];
#pragma unroll
      for (int u = 0; u < 8; ++u) {
        unsigned short h0 = f2bf(h[2 * u]), h1 = f2bf(h[2 * u + 1]);
        hp[u] = (unsigned int)h0 | ((unsigned int)h1 << 16);
        unsigned short l0 = f2bf(h[2 * u] - bf2f(h0));
        unsigned short l1 = f2bf(h[2 * u + 1] - bf2f(h1));
        lp[u] = (unsigned int)l0 | ((unsigned int)l1 << 16);
      }
      *(uint4*)&Ah[eloc * 40 + kb] = make_uint4(hp[0], hp[1], hp[2], hp[3]);
      *(uint4*)&Ah[eloc * 40 + kb + 8] =
          make_uint4(hp[4], hp[5], hp[6], hp[7]);
      *(uint4*)&Al[eloc * 40 + kb] = make_uint4(lp[0], lp[1], lp[2], lp[3]);
      *(uint4*)&Al[eloc * 40 + kb + 8] =
          make_uint4(lp[4], lp[5], lp[6], lp[7]);
    }
    {
      const size_t src = (size_t)eloc * 64 + k0 + kb;
      *(uint4*)&Bh[eloc * 40 + kb] = *(const uint4*)&W2ht[src];
      *(uint4*)&Bh[eloc * 40 + kb + 8] = *(const uint4*)&W2ht[src + 8];
      *(uint4*)&Bl[eloc * 40 + kb] = *(const uint4*)&W2lt[src];
      *(uint4*)&Bl[eloc * 40 + kb + 8] = *(const uint4*)&W2lt[src + 8];
    }
    __syncthreads();
    bf16x8 ah[2], al[2];
#pragma unroll
    for (int mt = 0; mt < 2; ++mt) {
      int row = w * 32 + mt * 16 + nidx;
      ah[mt] = *(const bf16x8*)&Ah[row * 40 + q * 8];
      al[mt] = *(const bf16x8*)&Al[row * 40 + q * 8];
    }
#pragma unroll
    for (int nt = 0; nt < 8; ++nt) {
      int col = nt * 16 + nidx;
      bf16x8 bh = *(const bf16x8*)&Bh[col * 40 + q * 8];
      bf16x8 bl = *(const bf16x8*)&Bl[col * 40 + q * 8];
#pragma unroll
      for (int mt = 0; mt < 2; ++mt) {
        acc[mt][nt] = __builtin_amdgcn_mfma_f32_16x16x32_bf16(
            ah[mt], bh, acc[mt][nt], 0, 0, 0);
        acc[mt][nt] = __builtin_amdgcn_mfma_f32_16x16x32_bf16(
            ah[mt], bl, acc[mt][nt], 0, 0, 0);
        acc[mt][nt] = __builtin_amdgcn_mfma_f32_16x16x32_bf16(
            al[mt], bh, acc[mt][nt], 0, 0, 0);
      }
    }
    __syncthreads();
  }

#pragma unroll
  for (int mt = 0; mt < 2; ++mt) {
    const int ebase = rowBase + w * 32 + mt * 16;
    const int pt0 = ebase >> 3;
#pragma unroll
    for (int nt = 0; nt < 8; ++nt) {
      f32x4 a = acc[mt][nt];
      float m = fmaxf(fmaxf(a[0], a[1]), fmaxf(a[2], a[3]));
      float o = fmaxf(m, __shfl_xor(m, 16, 64));
      int cg2 = nt * 16 + nidx;
      float val = fmaxf(o + b2[cg2], 0.0f);
      unsigned short h = f2bf(val);
      unsigned short l = f2bf(val - bf2f(h));
      if (q == 0) {
        yh[(size_t)pt0 * 128 + cg2] = h;
        yl[(size_t)pt0 * 128 + cg2] = l;
      } else if (q == 2) {
        yh[(size_t)(pt0 + 1) * 128 + cg2] = h;
        yl[(size_t)(pt0 + 1) * 128 + cg2] = l;
      }
    }
  }
}

// ---------------------------------------------------------------------------
// MFMA AC = y @ Wcat (+b3 on cols<128): A = yh/yl rows (no gather),
// B = Wcath/Wcatl. Tile 128x128, K=128 in 4 panels. Direct C-layout store.
// grid dim3(2, 64).
// ---------------------------------------------------------------------------
__global__ __launch_bounds__(256) void gemm_ac_mfma_kernel(
    const unsigned short* __restrict__ yh, const unsigned short* __restrict__ yl,
    const unsigned short* __restrict__ Wcath,
    const unsigned short* __restrict__ Wcatl, const float* __restrict__ b3,
    float* __restrict__ AC) {
  __shared__ unsigned short Ahs[128 * 40];
  __shared__ unsigned short Als[128 * 40];
  __shared__ unsigned short Bhs[128 * 40];
  __shared__ unsigned short Bls[128 * 40];
  const int t = threadIdx.x;
  const int rowBase = blockIdx.y * 128;
  const int colBase = blockIdx.x * 128;
  const int eloc = t >> 1, hh = t & 1;
  const int kb = hh * 16;
  const int lane = t & 63;
  const int w = t >> 6;
  const int q = lane >> 4;
  const int nidx = lane & 15;

  f32x4 acc[2][8];
#pragma unroll
  for (int mt = 0; mt < 2; ++mt)
#pragma unroll
    for (int nt = 0; nt < 8; ++nt) acc[mt][nt] = (f32x4){0.f, 0.f, 0.f, 0.f};

  for (int p = 0; p < 4; ++p) {
    const int k0 = p * 32;
    {
      const size_t srcA = (size_t)(rowBase + eloc) * 128 + k0 + kb;
      *(uint4*)&Ahs[eloc * 40 + kb] = *(const uint4*)&yh[srcA];
      *(uint4*)&Ahs[eloc * 40 + kb + 8] = *(const uint4*)&yh[srcA + 8];
      *(uint4*)&Als[eloc * 40 + kb] = *(const uint4*)&yl[srcA];
      *(uint4*)&Als[eloc * 40 + kb + 8] = *(const uint4*)&yl[srcA + 8];
      const size_t srcB = (size_t)(colBase + eloc) * 128 + k0 + kb;
      *(uint4*)&Bhs[eloc * 40 + kb] = *(const uint4*)&Wcath[srcB];
      *(uint4*)&Bhs[eloc * 40 + kb + 8] = *(const uint4*)&Wcath[srcB + 8];
      *(uint4*)&Bls[eloc * 40 + kb] = *(const uint4*)&Wcatl[srcB];
      *(uint4*)&Bls[eloc * 40 + kb + 8] = *(const uint4*)&Wcatl[srcB + 8];
    }
    __syncthreads();
    bf16x8 ah[2], al[2];
#pragma unroll
    for (int mt = 0; mt < 2; ++mt) {
      int row = w * 32 + mt * 16 + nidx;
      ah[mt] = *(const bf16x8*)&Ahs[row * 40 + q * 8];
      al[mt] = *(const bf16x8*)&Als[row * 40 + q * 8];
    }
#pragma unroll
    for (int nt = 0; nt < 8; ++nt) {
      int col = nt * 16 + nidx;
      bf16x8 bh = *(const bf16x8*)&Bhs[col * 40 + q * 8];
      bf16x8 bl = *(const bf16x8*)&Bls[col * 40 + q * 8];
#pragma unroll
      for (int mt = 0; mt < 2; ++mt) {
        acc[mt][nt] = __builtin_amdgcn_mfma_f32_16x16x32_bf16(
            ah[mt], bh, acc[mt][nt], 0, 0, 0);
        acc[mt][nt] = __builtin_amdgcn_mfma_f32_16x16x32_bf16(
            ah[mt], bl, acc[mt][nt], 0, 0, 0);
        acc[mt][nt] = __builtin_amdgcn_mfma_f32_16x16x32_bf16(
            al[mt], bh, acc[mt][nt], 0, 0, 0);
      }
    }
    __syncthreads();
  }

  // Direct C-layout store: row = quad*4+reg, col = nt*16+nidx.
#pragma unroll
  for (int mt = 0; mt < 2; ++mt) {
#pragma unroll
    for (int nt = 0; nt < 8; ++nt) {
      int gcol = colBase + nt * 16 + nidx;
      float bias = (gcol < 128) ? b3[gcol] : 0.0f;
      f32x4 a = acc[mt][nt];
#pragma unroll
      for (int reg = 0; reg < 4; ++reg) {
        int grow = rowBase + w * 32 + mt * 16 + q * 4 + reg;
        AC[(size_t)grow * 256 + gcol] = a[reg] + bias;
      }
    }
  }
}

// ---------------------------------------------------------------------------
// MFMA EdgeConv2 second layer (split-bf16), verified R7/R8.
// ---------------------------------------------------------------------------
__global__ __launch_bounds__(256) void gemm2_mfma_kernel(
    const float* __restrict__ AC, const int* __restrict__ nbr,
    const unsigned short* __restrict__ W4ht,
    const unsigned short* __restrict__ W4lt, const float* __restrict__ b4,
    float* __restrict__ out) {
  __shared__ unsigned short H2h[128 * 40];
  __shared__ unsigned short H2l[128 * 40];
  __shared__ unsigned short Wth[128 * 40];
  __shared__ unsigned short Wtl[128 * 40];
  const int t = threadIdx.x;
  const int rowBase = blockIdx.y * 128;
  const int colBase = blockIdx.x * 128;
  const int eloc = t >> 1, hh = t & 1;
  const int kb = hh * 16;
  const int edge = rowBase + eloc;
  const int ip = edge >> 3;
  const int jp = nbr[edge];
  const float* ai_p = AC + (size_t)ip * 256;
  const float* ci_p = ai_p + 128;
  const float* cj_p = AC + (size_t)jp * 256 + 128;
  const int lane = t & 63;
  const int w = t >> 6;
  const int q = lane >> 4;
  const int nidx = lane & 15;

  f32x4 acc[2][8];
#pragma unroll
  for (int mt = 0; mt < 2; ++mt)
#pragma unroll
    for (int nt = 0; nt < 8; ++nt) acc[mt][nt] = (f32x4){0.f, 0.f, 0.f, 0.f};

  for (int p = 0; p < 4; ++p) {
    const int k0 = p * 32;
    {
      float h2[16];
      const float4* a4 = (const float4*)(ai_p + k0 + kb);
      const float4* c4 = (const float4*)(ci_p + k0 + kb);
      const float4* d4 = (const float4*)(cj_p + k0 + kb);
#pragma unroll
      for (int u = 0; u < 4; ++u) {
        float4 a = a4[u], c = c4[u], d = d4[u];
        h2[u * 4 + 0] = fmaxf(a.x + d.x - c.x, 0.f);
        h2[u * 4 + 1] = fmaxf(a.y + d.y - c.y, 0.f);
        h2[u * 4 + 2] = fmaxf(a.z + d.z - c.z, 0.f);
        h2[u * 4 + 3] = fmaxf(a.w + d.w - c.w, 0.f);
      }
      unsigned int hp[8], lp[8];
#pragma unroll
      for (int u = 0; u < 8; ++u) {
        unsigned short h0 = f2bf(h2[2 * u]), h1 = f2bf(h2[2 * u + 1]);
        hp[u] = (unsigned int)h0 | ((unsigned int)h1 << 16);
        unsigned short l0 = f2bf(h2[2 * u] - bf2f(h0));
        unsigned short l1 = f2bf(h2[2 * u + 1] - bf2f(h1));
        lp[u] = (unsigned int)l0 | ((unsigned int)l1 << 16);
      }
      *(uint4*)&H2h[eloc * 40 + kb] = make_uint4(hp[0], hp[1], hp[2], hp[3]);
      *(uint4*)&H2h[eloc * 40 + kb + 8] =
          make_uint4(hp[4], hp[5], hp[6], hp[7]);
      *(uint4*)&H2l[eloc * 40 + kb] = make_uint4(lp[0], lp[1], lp[2], lp[3]);
      *(uint4*)&H2l[eloc * 40 + kb + 8] =
          make_uint4(lp[4], lp[5], lp[6], lp[7]);
    }
    {
      const size_t src = (size_t)(colBase + eloc) * 128 + k0 + kb;
      *(uint4*)&Wth[eloc * 40 + kb] = *(const uint4*)&W4ht[src];
      *(uint4*)&Wth[eloc * 40 + kb + 8] = *(const uint4*)&W4ht[src + 8];
      *(uint4*)&Wtl[eloc * 40 + kb] = *(const uint4*)&W4lt[src];
      *(uint4*)&Wtl[eloc * 40 + kb + 8] = *(const uint4*)&W4lt[src + 8];
    }
    __syncthreads();
    bf16x8 ah[2], al[2];
#pragma unroll
    for (int mt = 0; mt < 2; ++mt) {
      int row = w * 32 + mt * 16 + nidx;
      ah[mt] = *(const bf16x8*)&H2h[row * 40 + q * 8];
      al[mt] = *(const bf16x8*)&H2l[row * 40 + q * 8];
    }
#pragma unroll
    for (int nt = 0; nt < 8; ++nt) {
      int col = nt * 16 + nidx;
      bf16x8 bh = *(const bf16x8*)&Wth[col * 40 + q * 8];
      bf16x8 bl = *(const bf16x8*)&Wtl[col * 40 + q * 8];
#pragma unroll
      for (int mt = 0; mt < 2; ++mt) {
        acc[mt][nt] = __builtin_amdgcn_mfma_f32_16x16x32_bf16(
            ah[mt], bh, acc[mt][nt], 0, 0, 0);
        acc[mt][nt] = __builtin_amdgcn_mfma_f32_16x16x32_bf16(
            ah[mt], bl, acc[mt][nt], 0, 0, 0);
        acc[mt][nt] = __builtin_amdgcn_mfma_f32_16x16x32_bf16(
            al[mt], bh, acc[mt][nt], 0, 0, 0);
      }
    }
    __syncthreads();
  }

#pragma unroll
  for (int mt = 0; mt < 2; ++mt) {
    const int ebase = rowBase + w * 32 + mt * 16;
    const int pt0 = ebase >> 3;
#pragma unroll
    for (int nt = 0; nt < 8; ++nt) {
      f32x4 a = acc[mt][nt];
      float m = fmaxf(fmaxf(a[0], a[1]), fmaxf(a[2], a[3]));
      float o = fmaxf(m, __shfl_xor(m, 16, 64));
      int cg2 = colBase + nt * 16 + nidx;
      if (q == 0) {
        out[(size_t)pt0 * 256 + cg2] = o + b4[cg2];
      } else if (q == 2) {
        out[(size_t)(pt0 + 1) * 256 + cg2] = o + b4[cg2];
      }
    }
  }
}

extern "C" void kernel_launch(void* const* d_in, const int* in_sizes, int n_in,
                              void* d_out, int out_size, void* d_ws,
                              size_t ws_size, hipStream_t stream) {
  const float* pts = (const float*)d_in[0];
  const float* W1 = (const float*)d_in[1];
  const float* b1 = (const float*)d_in[2];
  const float* W2 = (const float*)d_in[3];
  const float* b2 = (const float*)d_in[4];
  const float* W3 = (const float*)d_in[5];
  const float* b3 = (const float*)d_in[6];
  const float* W4 = (const float*)d_in[7];
  const float* b4 = (const float*)d_in[8];
  float* out = (float*)d_out;

  float* w = (float*)d_ws;
  float* part_v = w;                                       // 1048576 f
  double* part_k = (double*)(w + 1048576);                 // 2097152 f
  int* nbr = (int*)(w + 3145728);                          // 65536 i
  unsigned short* yh = (unsigned short*)(w + 3211264);     // 1048576 us
  unsigned short* yl = (unsigned short*)(w + 3735552);     // 1048576 us
  float* AC = w + 4259840;                                 // 2097152 f
  unsigned short* Wcath = (unsigned short*)(w + 6356992);  // 32768 us
  unsigned short* Wcatl = (unsigned short*)(w + 6373376);  // 32768 us
  unsigned short* W4ht = (unsigned short*)(w + 6389760);   // 32768 us
  unsigned short* W4lt = (unsigned short*)(w + 6406144);   // 32768 us
  unsigned short* W2ht = (unsigned short*)(w + 6422528);   // 8192 us
  unsigned short* W2lt = (unsigned short*)(w + 6426624);   // 8192 us

  // Weight prep (independent of KNN)
  prep_kernel<<<288, 256, 0, stream>>>(W3, W4, W2, Wcath, Wcatl, W4ht, W4lt,
                                       W2ht, W2lt);

  // 1. KNN mega-kernel (cooperative): subset -> tau -> gated scan -> merge
  {
    void* args[] = {(void*)&pts, (void*)&part_v, (void*)&part_k, (void*)&nbr};
    hipLaunchCooperativeKernel((void*)knn_mega_kernel, dim3(512), dim3(256),
                               args, 0, stream);
  }

  // 2. EdgeConv1 (MFMA split-bf16) -> y in split-bf16
  gemm1_mfma_kernel<<<512, 256, 0, stream>>>(pts, nbr, W1, b1, W2ht, W2lt, b2,
                                             yh, yl);

  // 3. EdgeConv2: MFMA AC = y@Wcat (+b3), then MFMA H2+GEMM+max8+b4 -> out
  gemm_ac_mfma_kernel<<<dim3(2, 64), 256, 0, stream>>>(yh, yl, Wcath, Wcatl,
                                                       b3, AC);
  gemm2_mfma_kernel<<<dim3(2, 512), 256, 0, stream>>>(AC, nbr, W4ht, W4lt, b4,
                                                      out);
}